// Round 1
// baseline (47.059 us; speedup 1.0000x reference)
//
#include <hip/hip_runtime.h>

// LIF: T=8 time steps, tau=1, thresh=1.
// x: [T*B, F] fp32 viewed as [T, B*F]. Each neuron n in [0, B*F):
//   mem=0; for t: mem += x[t][n]; spike = (mem>=1)?1:0; out[t][n]=spike; if(spike) mem=0;
// Memory-bound: 128 MiB in + 128 MiB out.

#define LIF_T 8

__global__ __launch_bounds__(256) void lif_kernel(const float4* __restrict__ x,
                                                  float4* __restrict__ out,
                                                  int n4) {
    int i = blockIdx.x * blockDim.x + threadIdx.x;
    if (i >= n4) return;

    float4 mem = make_float4(0.f, 0.f, 0.f, 0.f);
#pragma unroll
    for (int t = 0; t < LIF_T; ++t) {
        float4 xt = x[(size_t)t * n4 + i];
        mem.x += xt.x;
        mem.y += xt.y;
        mem.z += xt.z;
        mem.w += xt.w;
        float4 sp;
        sp.x = (mem.x >= 1.0f) ? 1.0f : 0.0f;
        sp.y = (mem.y >= 1.0f) ? 1.0f : 0.0f;
        sp.z = (mem.z >= 1.0f) ? 1.0f : 0.0f;
        sp.w = (mem.w >= 1.0f) ? 1.0f : 0.0f;
        out[(size_t)t * n4 + i] = sp;
        mem.x = (sp.x != 0.0f) ? 0.0f : mem.x;
        mem.y = (sp.y != 0.0f) ? 0.0f : mem.y;
        mem.z = (sp.z != 0.0f) ? 0.0f : mem.z;
        mem.w = (sp.w != 0.0f) ? 0.0f : mem.w;
    }
}

extern "C" void kernel_launch(void* const* d_in, const int* in_sizes, int n_in,
                              void* d_out, int out_size, void* d_ws, size_t ws_size,
                              hipStream_t stream) {
    const float* x = (const float*)d_in[0];
    float* out = (float*)d_out;

    // total elements = T * B * F; per-timestep neurons = total / T
    long long total = (long long)in_sizes[0];
    int n = (int)(total / LIF_T);   // B*F = 4,194,304
    int n4 = n / 4;                 // float4 granules per timestep

    int block = 256;
    int grid = (n4 + block - 1) / block;
    lif_kernel<<<grid, block, 0, stream>>>((const float4*)x, (float4*)out, n4);
}

// Round 3
// 45.055 us; speedup vs baseline: 1.0445x; 1.0445x over previous
//
#include <hip/hip_runtime.h>

// LIF: T=8, tau=1, thresh=1. x: [T, B*F] fp32.
// mem=0; for t: mem += x[t][n]; spike=(mem>=1); out[t][n]=spike; if(spike) mem=0;
//
// Memory-bound. Input (128 MiB) fits in the 256 MiB Infinity Cache; output
// stores are non-temporal (nt flag, evict-first) so the write stream doesn't
// evict the input from L3 between graph replays.

#define LIF_T 8

typedef float f32x4 __attribute__((ext_vector_type(4)));

__global__ __launch_bounds__(256) void lif_kernel(const f32x4* __restrict__ x,
                                                  f32x4* __restrict__ out,
                                                  int n4) {
    int i = blockIdx.x * blockDim.x + threadIdx.x;
    if (i >= n4) return;

    f32x4 mem = (f32x4)(0.f);
#pragma unroll
    for (int t = 0; t < LIF_T; ++t) {
        f32x4 xt = x[(size_t)t * n4 + i];
        mem += xt;
        f32x4 sp;
        sp.x = (mem.x >= 1.0f) ? 1.0f : 0.0f;
        sp.y = (mem.y >= 1.0f) ? 1.0f : 0.0f;
        sp.z = (mem.z >= 1.0f) ? 1.0f : 0.0f;
        sp.w = (mem.w >= 1.0f) ? 1.0f : 0.0f;
        __builtin_nontemporal_store(sp, &out[(size_t)t * n4 + i]);
        mem.x = (sp.x != 0.0f) ? 0.0f : mem.x;
        mem.y = (sp.y != 0.0f) ? 0.0f : mem.y;
        mem.z = (sp.z != 0.0f) ? 0.0f : mem.z;
        mem.w = (sp.w != 0.0f) ? 0.0f : mem.w;
    }
}

extern "C" void kernel_launch(void* const* d_in, const int* in_sizes, int n_in,
                              void* d_out, int out_size, void* d_ws, size_t ws_size,
                              hipStream_t stream) {
    const float* x = (const float*)d_in[0];
    float* out = (float*)d_out;

    long long total = (long long)in_sizes[0];
    int n = (int)(total / LIF_T);   // B*F neurons per timestep
    int n4 = n / 4;                 // float4 granules

    int block = 256;
    int grid = (n4 + block - 1) / block;
    lif_kernel<<<grid, block, 0, stream>>>((const f32x4*)x, (f32x4*)out, n4);
}